// Round 9
// baseline (43.007 us; speedup 1.0000x reference)
//
#include <hip/hip_runtime.h>
#include <math.h>

// x: (8,16,512,64) fp32; flat = [wk | wq], each (64,4). Output: int32 top-12 idx.
constexpr int kDIn  = 64;
constexpr int kN    = 512;
constexpr int kTopK = 12;
constexpr int kNBt  = 128;          // 8*16
constexpr int kS    = 8;            // row-slices per tile
constexpr int kRows = kN / kS;      // 64 rows per block
// exp(SCALE*h) = exp2(CEXP*h); SCALE = 0.125; CEXP = SCALE*log2(e)
#define CEXP 0.18033688f
#define EXP2(v) __builtin_amdgcn_exp2f(v)
#define LOG2F(v) __builtin_amdgcn_logf(v)       // v_log_f32 = log base 2
// NUMERIC INVARIANT (R3/R5): every exp2 argument <= 0 via a true running/exact
// row max. Online variant: l >= 1 after each chunk; rescale factor <= 1
// (underflow benign). No denormal, no inf, immune to FTZ.

#define DOT4(k, q)        fmaf((k).x,(q).x, fmaf((k).y,(q).y, fmaf((k).z,(q).z, (k).w*(q).w)))
#define DOT4A(k, q, add)  fmaf((k).x,(q).x, fmaf((k).y,(q).y, fmaf((k).z,(q).z, fmaf((k).w,(q).w,(add)))))

// ws: apart [128][8][512] floats = 2 MB
constexpr size_t kWsFloats = (size_t)kNBt * kS * kN;

// ============ KA: fused projection + online rowstats + colsum partial ============
// grid 1024, block 512, 4 blocks/CU (32 waves/CU). Logical (tile, s): block owns
// 64 K-rows [s*64, s*64+64). XCD swizzle: p = (tile>>3)*64 + s*8 + (tile&7) ->
// all 8 same-tile blocks on one XCD (x tile stays L2-resident despite 8x reads).
__global__ __launch_bounds__(512, 8) void fused_attn_kernel(
    const float* __restrict__ x, const float* __restrict__ flat,
    float* __restrict__ apart)
{
  __shared__ float4 Wk[kDIn];
  __shared__ float4 Wq[kDIn];
  __shared__ float4 Qs[kN];          // unscaled Q, all 512 rows (8 KB)
  __shared__ float4 Ks[kRows];       // CEXP-scaled K, own slice (1 KB)
  __shared__ float2 Pp[kN];          // (m, l) partials per (js, row)
  __shared__ __align__(16) float Cs[kRows];  // c_i = m_i + log2(l_i)

  const int tid  = threadIdx.x;
  const int p    = blockIdx.x;
  const int xcd  = p & 7;
  const int s    = (p >> 3) & 7;
  const int tile = ((p >> 6) << 3) | xcd;

  if (tid < 64)       Wk[tid]      = reinterpret_cast<const float4*>(flat)[tid];
  else if (tid < 128) Wq[tid - 64] = reinterpret_cast<const float4*>(flat)[tid];
  __syncthreads();

  // ---- phase 1: thread t projects row t. Q always; K only for own slice ----
  {
    const float4* xr4 = reinterpret_cast<const float4*>(x + ((size_t)tile * kN + tid) * kDIn);
    float q0=0.f,q1=0.f,q2=0.f,q3=0.f;
    if ((tid >> 6) == s) {
      float k0=0.f,k1=0.f,k2=0.f,k3=0.f;
#pragma unroll
      for (int cc = 0; cc < kDIn / 4; ++cc) {
        float4 xv = xr4[cc];
#pragma unroll
        for (int u = 0; u < 4; ++u) {
          float v = (u==0)?xv.x:(u==1)?xv.y:(u==2)?xv.z:xv.w;
          float4 a = Wk[cc*4+u];
          float4 b = Wq[cc*4+u];
          k0 = fmaf(v, a.x, k0); k1 = fmaf(v, a.y, k1);
          k2 = fmaf(v, a.z, k2); k3 = fmaf(v, a.w, k3);
          q0 = fmaf(v, b.x, q0); q1 = fmaf(v, b.y, q1);
          q2 = fmaf(v, b.z, q2); q3 = fmaf(v, b.w, q3);
        }
      }
      Ks[tid & 63] = make_float4(CEXP*k0, CEXP*k1, CEXP*k2, CEXP*k3);
    } else {
#pragma unroll
      for (int cc = 0; cc < kDIn / 4; ++cc) {
        float4 xv = xr4[cc];
#pragma unroll
        for (int u = 0; u < 4; ++u) {
          float v = (u==0)?xv.x:(u==1)?xv.y:(u==2)?xv.z:xv.w;
          float4 b = Wq[cc*4+u];
          q0 = fmaf(v, b.x, q0); q1 = fmaf(v, b.y, q1);
          q2 = fmaf(v, b.z, q2); q3 = fmaf(v, b.w, q3);
        }
      }
    }
    Qs[tid] = make_float4(q0, q1, q2, q3);
  }
  __syncthreads();

  // ---- phase 2: ONLINE rowstats. thread = (row = tid&63, js = tid>>6) ----
  // wave w handles js = w: Qs reads are wave-uniform -> broadcast, conflict-free.
  {
    const float4 k = Ks[tid & 63];
    const float4* qb = &Qs[(tid >> 6) << 6];

    float m = -INFINITY, l0 = 0.f, l1 = 0.f;
#pragma unroll 2
    for (int c = 0; c < kRows; c += 8) {
      float4 qa = qb[c],   qb_ = qb[c+1], qc = qb[c+2], qd = qb[c+3];
      float4 qe = qb[c+4], qf  = qb[c+5], qg = qb[c+6], qh = qb[c+7];
      float h0 = DOT4(k, qa),  h1 = DOT4(k, qb_), h2 = DOT4(k, qc), h3 = DOT4(k, qd);
      float h4 = DOT4(k, qe),  h5 = DOT4(k, qf),  h6 = DOT4(k, qg), h7 = DOT4(k, qh);
      float cm = fmaxf(fmaxf(fmaxf(h0,h1), fmaxf(h2,h3)),
                       fmaxf(fmaxf(h4,h5), fmaxf(h6,h7)));
      if (cm > m) {            // factor <= 1; underflow benign
        float f = EXP2(m - cm);
        l0 *= f; l1 *= f; m = cm;
      }
      l0 += EXP2(h0 - m); l1 += EXP2(h1 - m);
      l0 += EXP2(h2 - m); l1 += EXP2(h3 - m);
      l0 += EXP2(h4 - m); l1 += EXP2(h5 - m);
      l0 += EXP2(h6 - m); l1 += EXP2(h7 - m);
    }
    Pp[tid] = make_float2(m, l0 + l1);
  }
  __syncthreads();
  if (tid < kRows) {
    // merge 8 j-slice partials (exact max, exp2-scaled sums; args <= 0)
    float2 p0 = Pp[tid],           p1 = Pp[tid + 64],  p2 = Pp[tid + 128], p3 = Pp[tid + 192];
    float2 p4 = Pp[tid + 256],     p5 = Pp[tid + 320], p6 = Pp[tid + 384], p7 = Pp[tid + 448];
    float m = fmaxf(fmaxf(fmaxf(p0.x,p1.x), fmaxf(p2.x,p3.x)),
                    fmaxf(fmaxf(p4.x,p5.x), fmaxf(p6.x,p7.x)));
    float l = fmaf(p0.y, EXP2(p0.x - m), p1.y * EXP2(p1.x - m)) +
              fmaf(p2.y, EXP2(p2.x - m), p3.y * EXP2(p3.x - m)) +
              fmaf(p4.y, EXP2(p4.x - m), p5.y * EXP2(p5.x - m)) +
              fmaf(p6.y, EXP2(p6.x - m), p7.y * EXP2(p7.x - m));
    Cs[tid] = m + LOG2F(l);        // l in [1,512] -> log2 in [0,9.01]
  }
  __syncthreads();

  // ---- phase 3: thread = column tid; own 64 rows' softmax weights ----
  {
    const float4 q = Qs[tid];
    float a0 = 0.f, a1 = 0.f;
#pragma unroll 4
    for (int i = 0; i < kRows; i += 4) {
      float4 k0 = Ks[i], k1 = Ks[i+1], k2 = Ks[i+2], k3 = Ks[i+3];
      float4 cc = *reinterpret_cast<const float4*>(&Cs[i]);
      a0 += EXP2(DOT4A(q, k0, -cc.x));
      a1 += EXP2(DOT4A(q, k1, -cc.y));
      a0 += EXP2(DOT4A(q, k2, -cc.z));
      a1 += EXP2(DOT4A(q, k3, -cc.w));
    }
    apart[((size_t)tile * kS + s) * kN + tid] = a0 + a1;
  }
}

// ============ KB: sum 8 partials + top-12; grid 128, block 64 ============
__global__ __launch_bounds__(64) void topk_kernel(
    const float* __restrict__ apart, int* __restrict__ out)
{
  const int lane = threadIdx.x;
  const int bt   = blockIdx.x;
  const float* P = apart + (size_t)bt * kS * kN;

  float v[8];
  {
    float4 acc0 = make_float4(0.f,0.f,0.f,0.f);
    float4 acc1 = make_float4(0.f,0.f,0.f,0.f);
#pragma unroll
    for (int s = 0; s < kS; ++s) {
      const float4* Ps = reinterpret_cast<const float4*>(P + s * kN);
      float4 u0 = Ps[lane*2], u1 = Ps[lane*2+1];
      acc0.x += u0.x; acc0.y += u0.y; acc0.z += u0.z; acc0.w += u0.w;
      acc1.x += u1.x; acc1.y += u1.y; acc1.z += u1.z; acc1.w += u1.w;
    }
    v[0]=acc0.x; v[1]=acc0.y; v[2]=acc0.z; v[3]=acc0.w;
    v[4]=acc1.x; v[5]=acc1.y; v[6]=acc1.z; v[7]=acc1.w;
  }

  for (int rnd = 0; rnd < kTopK; ++rnd) {
    float bv = v[0];
    int   bi = lane * 8;
#pragma unroll
    for (int r = 1; r < 8; ++r) {
      if (v[r] > bv) { bv = v[r]; bi = lane * 8 + r; }
    }
#pragma unroll
    for (int off = 32; off >= 1; off >>= 1) {
      float ov = __shfl_xor(bv, off);
      int   oi = __shfl_xor(bi, off);
      if (ov > bv || (ov == bv && oi < bi)) { bv = ov; bi = oi; }
    }
    if (lane == 0) out[bt * kTopK + rnd] = bi;
#pragma unroll
    for (int r = 0; r < 8; ++r) {
      if (lane * 8 + r == bi) v[r] = -INFINITY;
    }
  }
}

// ============ fallback: round-1 single kernel (ws too small / unexpected shape) ============
__global__ __launch_bounds__(512, 1) void sparse_attn_topk_fallback(
    const float* __restrict__ x, const float* __restrict__ flat, int* __restrict__ out)
{
  __shared__ float4 wk4[kDIn];
  __shared__ float4 wq4[kDIn];
  __shared__ float4 Ks[kN];
  __shared__ float4 Qs[kN];
  __shared__ float  Ms[kN];
  __shared__ float  Rl[kN];
  __shared__ float  As[kN];

  const int tid = threadIdx.x;
  const int bt  = blockIdx.x;

  if (tid < 64)       wk4[tid]      = reinterpret_cast<const float4*>(flat)[tid];
  else if (tid < 128) wq4[tid - 64] = reinterpret_cast<const float4*>(flat)[tid];
  __syncthreads();

  const float* xr = x + ((size_t)bt * kN + tid) * kDIn;
  float k0=0.f,k1=0.f,k2=0.f,k3=0.f, q0=0.f,q1=0.f,q2=0.f,q3=0.f;
#pragma unroll
  for (int c = 0; c < kDIn; ++c) {
    float xv = xr[c];
    float4 a = wk4[c];
    float4 b = wq4[c];
    k0 = fmaf(xv, a.x, k0); k1 = fmaf(xv, a.y, k1);
    k2 = fmaf(xv, a.z, k2); k3 = fmaf(xv, a.w, k3);
    q0 = fmaf(xv, b.x, q0); q1 = fmaf(xv, b.y, q1);
    q2 = fmaf(xv, b.z, q2); q3 = fmaf(xv, b.w, q3);
  }
  Ks[tid] = make_float4(k0, k1, k2, k3);
  Qs[tid] = make_float4(q0, q1, q2, q3);
  __syncthreads();

  float m = -INFINITY;
#pragma unroll 8
  for (int j = 0; j < kN; ++j) {
    float4 qj = Qs[j];
    float h = fmaf(k0, qj.x, fmaf(k1, qj.y, fmaf(k2, qj.z, k3 * qj.w)));
    m = fmaxf(m, h);
  }
  float l = 0.f;
#pragma unroll 8
  for (int j = 0; j < kN; ++j) {
    float4 qj = Qs[j];
    float h = fmaf(k0, qj.x, fmaf(k1, qj.y, fmaf(k2, qj.z, k3 * qj.w)));
    l += exp2f(CEXP * (h - m));
  }
  Ms[tid] = m;
  Rl[tid] = 1.0f / l;
  __syncthreads();

  float acc = 0.f;
#pragma unroll 8
  for (int i = 0; i < kN; ++i) {
    float4 ki = Ks[i];
    float h = fmaf(q0, ki.x, fmaf(q1, ki.y, fmaf(q2, ki.z, q3 * ki.w)));
    acc += exp2f(CEXP * (h - Ms[i])) * Rl[i];
  }
  As[tid] = acc;
  __syncthreads();

  if (tid < 64) {
    float v[8];
#pragma unroll
    for (int r = 0; r < 8; ++r) v[r] = As[tid * 8 + r];
    for (int rnd = 0; rnd < kTopK; ++rnd) {
      float bv = v[0];
      int   bi = tid * 8;
#pragma unroll
      for (int r = 1; r < 8; ++r)
        if (v[r] > bv) { bv = v[r]; bi = tid * 8 + r; }
#pragma unroll
      for (int off = 32; off >= 1; off >>= 1) {
        float ov = __shfl_xor(bv, off);
        int   oi = __shfl_xor(bi, off);
        if (ov > bv || (ov == bv && oi < bi)) { bv = ov; bi = oi; }
      }
      if (tid == 0) out[bt * kTopK + rnd] = bi;
#pragma unroll
      for (int r = 0; r < 8; ++r)
        if (tid * 8 + r == bi) v[r] = -INFINITY;
    }
  }
}

extern "C" void kernel_launch(void* const* d_in, const int* in_sizes, int n_in,
                              void* d_out, int out_size, void* d_ws, size_t ws_size,
                              hipStream_t stream) {
  const float* x    = (const float*)d_in[0];
  const float* flat = (const float*)d_in[1];
  int* out = (int*)d_out;
  const int n_bt = in_sizes[0] / (kN * kDIn);

  if (n_bt != kNBt || ws_size < kWsFloats * sizeof(float)) {
    sparse_attn_topk_fallback<<<n_bt, kN, 0, stream>>>(x, flat, out);
    return;
  }
  float* apart = (float*)d_ws;
  fused_attn_kernel<<<kNBt * kS, 512, 0, stream>>>(x, flat, apart);
  topk_kernel      <<<kNBt,       64, 0, stream>>>(apart, out);
}

// Round 10
// 40.382 us; speedup vs baseline: 1.0650x; 1.0650x over previous
//
#include <hip/hip_runtime.h>
#include <math.h>

// x: (8,16,512,64) fp32; flat = [wk | wq], each (64,4). Output: int32 top-12 idx.
constexpr int kDIn  = 64;
constexpr int kN    = 512;
constexpr int kTopK = 12;
constexpr int kNBt  = 128;          // 8*16
constexpr int kS    = 4;            // row-slices per tile (R8 best config)
constexpr int kRows = kN / kS;      // 128 rows per block
// exp(SCALE*h) = exp2(CEXP*h); SCALE = 0.125; CEXP = SCALE*log2(e)
#define CEXP 0.18033688f
#define EXP2(v) __builtin_amdgcn_exp2f(v)
#define LOG2F(v) __builtin_amdgcn_logf(v)       // v_log_f32 = log base 2
// NUMERIC INVARIANT (R3/R5): every exp2 argument <= 0 via an EXACT row max
// (two-pass per slice + exact merge). Terms in [0,1], l in [1,512] -- no
// denormal, no inf, immune to FTZ.

#define DOT4(k, q)        fmaf((k).x,(q).x, fmaf((k).y,(q).y, fmaf((k).z,(q).z, (k).w*(q).w)))
#define DOT4A(k, q, add)  fmaf((k).x,(q).x, fmaf((k).y,(q).y, fmaf((k).z,(q).z, fmaf((k).w,(q).w,(add)))))

// ws: apart [128 tiles][16 slices][512 cols] floats = 4 MB
constexpr size_t kWsFloats = (size_t)kNBt * 16 * kN;

// ============ KA: fused projection + rowstats + colsum, register-tiled ============
// grid 512, block 512, 2 blocks/CU. Logical (tile, s): block owns 128 K-rows
// [s*128, ...). XCD swizzle keeps the 4 same-tile blocks on one XCD (x tile
// L2-resident). LDS-PIPE BUDGET is the design driver (R9 post-mortem): each
// ds_read_b128 feeds 4 dot-products via register tiling.
__global__ __launch_bounds__(512, 4) void fused_attn_kernel(
    const float* __restrict__ x, const float* __restrict__ flat,
    float* __restrict__ apart)
{
  __shared__ float4 Wk[kDIn];
  __shared__ float4 Wq[kDIn];
  __shared__ float4 Qs[kN];                    // unscaled Q (8 KB)
  __shared__ float4 Ks[kRows];                 // CEXP-scaled K, own slice (2 KB)
  __shared__ float2 Pp[16 * kRows];            // (m,l) per (j-slice, row) (16 KB)
  __shared__ __align__(16) float Cs[kRows];    // c_i = m_i + log2(l_i)

  const int tid  = threadIdx.x;
  const int p    = blockIdx.x;
  const int xcd  = p & 7;
  const int s    = (p >> 3) & 3;
  const int tile = ((p >> 5) << 3) | xcd;

  if (tid < 64)       Wk[tid]      = reinterpret_cast<const float4*>(flat)[tid];
  else if (tid < 128) Wq[tid - 64] = reinterpret_cast<const float4*>(flat)[tid];
  __syncthreads();

  // ---- phase 1: thread t projects row t. Q always; K only for own quarter ----
  {
    const float4* xr4 = reinterpret_cast<const float4*>(x + ((size_t)tile * kN + tid) * kDIn);
    float q0=0.f,q1=0.f,q2=0.f,q3=0.f;
    if ((tid >> 7) == s) {
      float k0=0.f,k1=0.f,k2=0.f,k3=0.f;
#pragma unroll
      for (int cc = 0; cc < kDIn / 4; ++cc) {
        float4 xv = xr4[cc];
#pragma unroll
        for (int u = 0; u < 4; ++u) {
          float v = (u==0)?xv.x:(u==1)?xv.y:(u==2)?xv.z:xv.w;
          float4 a = Wk[cc*4+u];
          float4 b = Wq[cc*4+u];
          k0 = fmaf(v, a.x, k0); k1 = fmaf(v, a.y, k1);
          k2 = fmaf(v, a.z, k2); k3 = fmaf(v, a.w, k3);
          q0 = fmaf(v, b.x, q0); q1 = fmaf(v, b.y, q1);
          q2 = fmaf(v, b.z, q2); q3 = fmaf(v, b.w, q3);
        }
      }
      Ks[tid & 127] = make_float4(CEXP*k0, CEXP*k1, CEXP*k2, CEXP*k3);
    } else {
#pragma unroll
      for (int cc = 0; cc < kDIn / 4; ++cc) {
        float4 xv = xr4[cc];
#pragma unroll
        for (int u = 0; u < 4; ++u) {
          float v = (u==0)?xv.x:(u==1)?xv.y:(u==2)?xv.z:xv.w;
          float4 b = Wq[cc*4+u];
          q0 = fmaf(v, b.x, q0); q1 = fmaf(v, b.y, q1);
          q2 = fmaf(v, b.z, q2); q3 = fmaf(v, b.w, q3);
        }
      }
    }
    Qs[tid] = make_float4(q0, q1, q2, q3);
  }
  __syncthreads();

  // ---- phase 2: rowstats, register-tiled. thread = (row-quad, j-slice) ----
  // quad = tid&31 -> rows quad*4..+3 (K in 16 VGPRs); slice = tid>>5 -> j in
  // [slice*32,+32). Each Qs read feeds 4 dots. Two-pass exact max per slice.
  {
    const int quad  = tid & 31;
    const int slice = tid >> 5;
    const float4 k0 = Ks[quad*4+0], k1 = Ks[quad*4+1];
    const float4 k2 = Ks[quad*4+2], k3 = Ks[quad*4+3];
    const float4* qb = &Qs[slice << 5];   // 2 addrs/wave -> 2-way broadcast (free)

    float m0=-INFINITY, m1=-INFINITY, m2=-INFINITY, m3=-INFINITY;
#pragma unroll 4
    for (int j = 0; j < 32; ++j) {
      float4 q = qb[j];
      m0 = fmaxf(m0, DOT4(k0, q));
      m1 = fmaxf(m1, DOT4(k1, q));
      m2 = fmaxf(m2, DOT4(k2, q));
      m3 = fmaxf(m3, DOT4(k3, q));
    }
    float l0=0.f, l1=0.f, l2=0.f, l3=0.f;
#pragma unroll 4
    for (int j = 0; j < 32; ++j) {
      float4 q = qb[j];
      l0 += EXP2(DOT4A(k0, q, -m0));
      l1 += EXP2(DOT4A(k1, q, -m1));
      l2 += EXP2(DOT4A(k2, q, -m2));
      l3 += EXP2(DOT4A(k3, q, -m3));
    }
    // rows quad*4..+3 of slice: 4 consecutive float2 = 2 float4 stores
    float4* pp4 = reinterpret_cast<float4*>(&Pp[slice * kRows + quad*4]);
    pp4[0] = make_float4(m0, l0, m1, l1);
    pp4[1] = make_float4(m2, l2, m3, l3);
  }
  __syncthreads();

  // ---- merge 16 j-slice partials per row (exact max, scaled sums) ----
  if (tid < kRows) {
    float m = -INFINITY;
    float2 pr[16];
#pragma unroll
    for (int sl = 0; sl < 16; ++sl) {
      pr[sl] = Pp[sl * kRows + tid];
      m = fmaxf(m, pr[sl].x);
    }
    float l = 0.f;
#pragma unroll
    for (int sl = 0; sl < 16; ++sl) l += pr[sl].y * EXP2(pr[sl].x - m);
    Cs[tid] = m + LOG2F(l);            // l in [1,512]
  }
  __syncthreads();

  // ---- phase 3: colsum, register-tiled. thread = (col-quad, row-slice) ----
  // cq = tid&127 -> cols cq*4..+3 (Q in 16 VGPRs); rs = tid>>7 -> rows
  // [rs*32,+32). Ks read wave-uniform broadcast; Cs read as float4 per 4 rows.
  {
    const int cq = tid & 127;
    const int rs = tid >> 7;
    const float4 q0 = Qs[cq*4+0], q1 = Qs[cq*4+1];
    const float4 q2 = Qs[cq*4+2], q3 = Qs[cq*4+3];
    const float4* kb = &Ks[rs << 5];                                   // uniform/wave
    const float4* cb = reinterpret_cast<const float4*>(&Cs[rs << 5]);  // uniform/wave

    float a0=0.f, a1=0.f, a2=0.f, a3=0.f;
#pragma unroll 2
    for (int ii = 0; ii < 8; ++ii) {
      float4 cc = cb[ii];
      float4 ka = kb[ii*4+0], kb_ = kb[ii*4+1], kc = kb[ii*4+2], kd = kb[ii*4+3];
      a0 += EXP2(DOT4A(q0, ka, -cc.x));  a1 += EXP2(DOT4A(q1, ka, -cc.x));
      a2 += EXP2(DOT4A(q2, ka, -cc.x));  a3 += EXP2(DOT4A(q3, ka, -cc.x));
      a0 += EXP2(DOT4A(q0, kb_, -cc.y)); a1 += EXP2(DOT4A(q1, kb_, -cc.y));
      a2 += EXP2(DOT4A(q2, kb_, -cc.y)); a3 += EXP2(DOT4A(q3, kb_, -cc.y));
      a0 += EXP2(DOT4A(q0, kc, -cc.z));  a1 += EXP2(DOT4A(q1, kc, -cc.z));
      a2 += EXP2(DOT4A(q2, kc, -cc.z));  a3 += EXP2(DOT4A(q3, kc, -cc.z));
      a0 += EXP2(DOT4A(q0, kd, -cc.w));  a1 += EXP2(DOT4A(q1, kd, -cc.w));
      a2 += EXP2(DOT4A(q2, kd, -cc.w));  a3 += EXP2(DOT4A(q3, kd, -cc.w));
    }
    // cols cq*4..+3 contiguous -> one float4 store
    reinterpret_cast<float4*>(apart + ((size_t)(tile*4 + s) * 4 + rs) * kN)[cq] =
        make_float4(a0, a1, a2, a3);
  }
}

// ============ KB: sum 16 partials + top-12; grid 128, block 64 ============
__global__ __launch_bounds__(64) void topk_kernel(
    const float* __restrict__ apart, int* __restrict__ out)
{
  const int lane = threadIdx.x;
  const int bt   = blockIdx.x;
  const float* P = apart + (size_t)bt * 16 * kN;

  float v[8];
  {
    float4 acc0 = make_float4(0.f,0.f,0.f,0.f);
    float4 acc1 = make_float4(0.f,0.f,0.f,0.f);
#pragma unroll
    for (int sl = 0; sl < 16; ++sl) {
      const float4* Ps = reinterpret_cast<const float4*>(P + sl * kN);
      float4 u0 = Ps[lane*2], u1 = Ps[lane*2+1];
      acc0.x += u0.x; acc0.y += u0.y; acc0.z += u0.z; acc0.w += u0.w;
      acc1.x += u1.x; acc1.y += u1.y; acc1.z += u1.z; acc1.w += u1.w;
    }
    v[0]=acc0.x; v[1]=acc0.y; v[2]=acc0.z; v[3]=acc0.w;
    v[4]=acc1.x; v[5]=acc1.y; v[6]=acc1.z; v[7]=acc1.w;
  }

  for (int rnd = 0; rnd < kTopK; ++rnd) {
    float bv = v[0];
    int   bi = lane * 8;
#pragma unroll
    for (int r = 1; r < 8; ++r) {
      if (v[r] > bv) { bv = v[r]; bi = lane * 8 + r; }
    }
#pragma unroll
    for (int off = 32; off >= 1; off >>= 1) {
      float ov = __shfl_xor(bv, off);
      int   oi = __shfl_xor(bi, off);
      if (ov > bv || (ov == bv && oi < bi)) { bv = ov; bi = oi; }
    }
    if (lane == 0) out[bt * kTopK + rnd] = bi;
#pragma unroll
    for (int r = 0; r < 8; ++r) {
      if (lane * 8 + r == bi) v[r] = -INFINITY;
    }
  }
}

// ============ fallback: round-1 single kernel (ws too small / unexpected shape) ============
__global__ __launch_bounds__(512, 1) void sparse_attn_topk_fallback(
    const float* __restrict__ x, const float* __restrict__ flat, int* __restrict__ out)
{
  __shared__ float4 wk4[kDIn];
  __shared__ float4 wq4[kDIn];
  __shared__ float4 Ks[kN];
  __shared__ float4 Qs[kN];
  __shared__ float  Ms[kN];
  __shared__ float  Rl[kN];
  __shared__ float  As[kN];

  const int tid = threadIdx.x;
  const int bt  = blockIdx.x;

  if (tid < 64)       wk4[tid]      = reinterpret_cast<const float4*>(flat)[tid];
  else if (tid < 128) wq4[tid - 64] = reinterpret_cast<const float4*>(flat)[tid];
  __syncthreads();

  const float* xr = x + ((size_t)bt * kN + tid) * kDIn;
  float k0=0.f,k1=0.f,k2=0.f,k3=0.f, q0=0.f,q1=0.f,q2=0.f,q3=0.f;
#pragma unroll
  for (int c = 0; c < kDIn; ++c) {
    float xv = xr[c];
    float4 a = wk4[c];
    float4 b = wq4[c];
    k0 = fmaf(xv, a.x, k0); k1 = fmaf(xv, a.y, k1);
    k2 = fmaf(xv, a.z, k2); k3 = fmaf(xv, a.w, k3);
    q0 = fmaf(xv, b.x, q0); q1 = fmaf(xv, b.y, q1);
    q2 = fmaf(xv, b.z, q2); q3 = fmaf(xv, b.w, q3);
  }
  Ks[tid] = make_float4(k0, k1, k2, k3);
  Qs[tid] = make_float4(q0, q1, q2, q3);
  __syncthreads();

  float m = -INFINITY;
#pragma unroll 8
  for (int j = 0; j < kN; ++j) {
    float4 qj = Qs[j];
    float h = fmaf(k0, qj.x, fmaf(k1, qj.y, fmaf(k2, qj.z, k3 * qj.w)));
    m = fmaxf(m, h);
  }
  float l = 0.f;
#pragma unroll 8
  for (int j = 0; j < kN; ++j) {
    float4 qj = Qs[j];
    float h = fmaf(k0, qj.x, fmaf(k1, qj.y, fmaf(k2, qj.z, k3 * qj.w)));
    l += exp2f(CEXP * (h - m));
  }
  Ms[tid] = m;
  Rl[tid] = 1.0f / l;
  __syncthreads();

  float acc = 0.f;
#pragma unroll 8
  for (int i = 0; i < kN; ++i) {
    float4 ki = Ks[i];
    float h = fmaf(q0, ki.x, fmaf(q1, ki.y, fmaf(q2, ki.z, q3 * ki.w)));
    acc += exp2f(CEXP * (h - Ms[i])) * Rl[i];
  }
  As[tid] = acc;
  __syncthreads();

  if (tid < 64) {
    float v[8];
#pragma unroll
    for (int r = 0; r < 8; ++r) v[r] = As[tid * 8 + r];
    for (int rnd = 0; rnd < kTopK; ++rnd) {
      float bv = v[0];
      int   bi = tid * 8;
#pragma unroll
      for (int r = 1; r < 8; ++r)
        if (v[r] > bv) { bv = v[r]; bi = tid * 8 + r; }
#pragma unroll
      for (int off = 32; off >= 1; off >>= 1) {
        float ov = __shfl_xor(bv, off);
        int   oi = __shfl_xor(bi, off);
        if (ov > bv || (ov == bv && oi < bi)) { bv = ov; bi = oi; }
      }
      if (tid == 0) out[bt * kTopK + rnd] = bi;
#pragma unroll
      for (int r = 0; r < 8; ++r)
        if (tid * 8 + r == bi) v[r] = -INFINITY;
    }
  }
}

extern "C" void kernel_launch(void* const* d_in, const int* in_sizes, int n_in,
                              void* d_out, int out_size, void* d_ws, size_t ws_size,
                              hipStream_t stream) {
  const float* x    = (const float*)d_in[0];
  const float* flat = (const float*)d_in[1];
  int* out = (int*)d_out;
  const int n_bt = in_sizes[0] / (kN * kDIn);

  if (n_bt != kNBt || ws_size < kWsFloats * sizeof(float)) {
    sparse_attn_topk_fallback<<<n_bt, kN, 0, stream>>>(x, flat, out);
    return;
  }
  float* apart = (float*)d_ws;
  fused_attn_kernel<<<kNBt * kS, 512, 0, stream>>>(x, flat, apart);
  topk_kernel      <<<kNBt,       64, 0, stream>>>(apart, out);
}